// Round 9
// baseline (101.659 us; speedup 1.0000x reference)
//
#include <hip/hip_runtime.h>

// DeformConv2D b=4,c=128,H=W=64,outc=128,KS=3,PAD=1,N=9
// 2-launch pipeline (mode 3):
//   prep  : wfrag + xpose + desc + zero(out), fused, branch on blockIdx
//   splitk: grid 768 = b4*i64*kh3, block = 64px x 128o, taps 3kh..3kh+2.
//           wave = 16-o tile x 64 px (4 accs share each afrag).
//           paired half-wave dwordx2 gathers; epilogue = atomicAdd into out.
// Fallback (mode<=2): round-5 fused kernel (verified).

typedef __bf16  v8bf16 __attribute__((ext_vector_type(8)));
typedef __bf16  bf16x2 __attribute__((ext_vector_type(2)));
typedef __bf16  bf16x4 __attribute__((ext_vector_type(4)));
typedef float   f32x4  __attribute__((ext_vector_type(4)));
typedef unsigned short ushort4v __attribute__((ext_vector_type(4)));
typedef _Float16 half4v __attribute__((ext_vector_type(4)));

#define CIN  128
#define NPT  9
#define KTOT 1152
#define OC   128
#define PX   32
#define NDESC (NPT * PX)
#define KSTEPS 36
#define KSC  12
#define LDBc 392
#define DTOT (9 * 4 * 64 * 64)   // 147456
#define PXR  64                  // full row
#define LDR  392                 // 3*128+8

// prep grid layout
#define PB_WFRAG 72              // 72*256 = 18432 threads
#define PB_XPOSE 1024
#define PB_DESC  576             // 576*256 = 147456
#define PB_ZERO  2048            // 2048*256*4 = 2097152 floats
#define PB_TOTAL (PB_WFRAG + PB_XPOSE + PB_DESC + PB_ZERO)

__device__ __forceinline__ void desc_compute(const float* __restrict__ off, int t,
                                             uint4* __restrict__ desc) {
    int j   = t & 63;
    int i   = (t >> 6) & 63;
    int b   = (t >> 12) & 3;
    int tap = t >> 14;

    float ox = off[(((b * 18) + 2 * tap) << 12) + (i << 6) + j];
    float oy = off[(((b * 18) + 2 * tap + 1) << 12) + (i << 6) + j];
    float px = (float)(i + tap / 3) + ox;
    float py = (float)(j + tap % 3) + oy;
    float fx = floorf(px), fy = floorf(py);
    int qltx = (int)fminf(fmaxf(fx, 0.f), 65.f);
    int qlty = (int)fminf(fmaxf(fy, 0.f), 65.f);
    int qrbx = (int)fminf(fmaxf(fx + 1.f, 0.f), 65.f);
    int qrby = (int)fminf(fmaxf(fy + 1.f, 0.f), 65.f);
    if (px < 1.f || px > 64.f) px = fx;
    if (py < 1.f || py > 64.f) py = fy;
    px = fminf(fmaxf(px, 0.f), 65.f);
    py = fminf(fmaxf(py, 0.f), 65.f);
    float wxl = 1.f + (float)qltx - px;
    float wxr = 1.f - ((float)qrbx - px);
    float wyl = 1.f + (float)qlty - py;
    float wyr = 1.f - ((float)qrby - py);
    float g[4] = { wxl * wyl, wxr * wyr, wxl * wyr, wxr * wyl };
    int qx[4] = { qltx, qrbx, qltx, qrbx };
    int qy[4] = { qlty, qrby, qrby, qlty };
    unsigned short idx[4];
    half4v gh;
    #pragma unroll
    for (int cr = 0; cr < 4; ++cr) {
        bool inb = (qx[cr] >= 1) && (qx[cr] <= 64) && (qy[cr] >= 1) && (qy[cr] <= 64);
        idx[cr] = inb ? (unsigned short)((qx[cr] - 1) * 64 + (qy[cr] - 1)) : 0;
        gh[cr]  = inb ? (_Float16)g[cr] : (_Float16)0.f;
    }
    uint4 rec;
    rec.x = (unsigned)idx[0] | ((unsigned)idx[1] << 16);
    rec.y = (unsigned)idx[2] | ((unsigned)idx[3] << 16);
    __builtin_memcpy(&rec.z, &gh, 8);
    int d = (((b << 6) + i) * 64 + j) * 9 + tap;
    desc[d] = rec;
}

// ---------- fused prep: wfrag | xpose | desc | zero(out) ----------
__global__ __launch_bounds__(256) void prep_kernel(
    const float* __restrict__ x, const float* __restrict__ off,
    const float* __restrict__ w, __bf16* __restrict__ wfrag,
    __bf16* __restrict__ xt, uint4* __restrict__ desc,
    float* __restrict__ out)
{
    __shared__ float tile[64][33];
    const int bid = blockIdx.x;
    const int tid = threadIdx.x;

    if (bid < PB_WFRAG) {
        int t = bid * 256 + tid;
        if (t < 8 * KSTEPS * 64) {
            int lane = t & 63;
            int ks   = (t >> 6) % KSTEPS;
            int ot   = t / (KSTEPS * 64);
            int o    = ot * 16 + (lane & 15);
            v8bf16 frag;
            #pragma unroll
            for (int e = 0; e < 8; ++e) {
                int k   = ks * 32 + (lane >> 4) * 8 + e;
                int tap = k >> 7, c = k & 127;
                frag[e] = (__bf16)w[(size_t)o * KTOT + c * NPT + tap];
            }
            *(v8bf16*)(wfrag + (size_t)t * 8) = frag;
        }
    } else if (bid < PB_WFRAG + PB_XPOSE) {
        const int bidx = bid - PB_WFRAG;
        const int b   = bidx >> 8;
        const int hw0 = ((bidx >> 2) & 63) * 64;
        const int c0  = (bidx & 3) * 32;
        #pragma unroll
        for (int r = 0; r < 8; ++r) {
            int c_l  = (tid >> 6) + r * 4;
            int hw_l = tid & 63;
            tile[hw_l][c_l] = x[((size_t)(b * CIN + c0 + c_l) << 12) + hw0 + hw_l];
        }
        __syncthreads();
        #pragma unroll
        for (int r = 0; r < 8; ++r) {
            int hw_l = (tid >> 5) + r * 8;
            int c_l  = tid & 31;
            xt[((size_t)(b * 4096 + hw0 + hw_l)) * CIN + c0 + c_l] = (__bf16)tile[hw_l][c_l];
        }
    } else if (bid < PB_WFRAG + PB_XPOSE + PB_DESC) {
        int t = (bid - PB_WFRAG - PB_XPOSE) * 256 + tid;
        if (t < DTOT) desc_compute(off, t, desc);
    } else {
        int t = (bid - PB_WFRAG - PB_XPOSE - PB_DESC) * 256 + tid;
        f32x4 z = {0.f, 0.f, 0.f, 0.f};
        *(f32x4*)(out + (size_t)t * 4) = z;
    }
}

// ---------- split-K=3 full-row kernel, atomic epilogue ----------
__global__ __launch_bounds__(512, 6) void splitk_kernel(
    const uint4* __restrict__ desc, const __bf16* __restrict__ xt,
    const __bf16* __restrict__ wfrag, float* __restrict__ out)
{
    __shared__ __align__(16) __bf16 Bt[PXR][LDR];   // 50176 B

    const int bidx = blockIdx.x;     // 768 = b(4) * i(64) * kh(3)
    const int kh3 = bidx % 3;
    const int rest = bidx / 3;
    const int i   = rest & 63;
    const int b   = rest >> 6;
    const int tid = threadIdx.x;

    const int tap0 = kh3 * 3;

    const int l  = tid & 63;
    const int wv = tid >> 6;            // 0..7

    const __bf16* xtb = xt + (((size_t)b << 12) * CIN);
    const int pix_base = ((b << 6) + i) * 64;

    // ---- stage: 192 descs (3 taps x 64 px), 24 per wave, 2 per iter ----
    const int hh = l >> 5;      // half-wave: 0 or 1
    const int ll = l & 31;
    #pragma unroll 3
    for (int m = 0; m < 12; ++m) {
        int dl = wv * 24 + 2 * m + hh;    // [0,192)
        int tap_l = dl >> 6, p = dl & 63;
        int d = (pix_base + p) * 9 + tap0 + tap_l;
        uint4 q = desc[d];
        unsigned short idx[4] = { (unsigned short)(q.x & 0xffff), (unsigned short)(q.x >> 16),
                                  (unsigned short)(q.y & 0xffff), (unsigned short)(q.y >> 16) };
        half4v gh;
        __builtin_memcpy(&gh, &q.z, 8);
        float s0 = 0.f, s1 = 0.f, s2 = 0.f, s3 = 0.f;
        #pragma unroll
        for (int cr = 0; cr < 4; ++cr) {
            uint2 v = *(const uint2*)(xtb + (size_t)idx[cr] * CIN + 4 * ll);
            float c0v, c1v, c2v, c3v;
            unsigned int l0 = v.x << 16, h0 = v.x & 0xffff0000u;
            unsigned int l1 = v.y << 16, h1 = v.y & 0xffff0000u;
            __builtin_memcpy(&c0v, &l0, 4);
            __builtin_memcpy(&c1v, &h0, 4);
            __builtin_memcpy(&c2v, &l1, 4);
            __builtin_memcpy(&c3v, &h1, 4);
            float gf = (float)gh[cr];
            s0 += gf * c0v;
            s1 += gf * c1v;
            s2 += gf * c2v;
            s3 += gf * c3v;
        }
        bf16x4 pr = { (__bf16)s0, (__bf16)s1, (__bf16)s2, (__bf16)s3 };
        *(bf16x4*)&Bt[p][tap_l * CIN + 4 * ll] = pr;
    }
    __syncthreads();

    // ---- MFMA: wave = ot (wv), 4 px-quarters share each afrag ----
    const int quad = l >> 4;
    const int lr   = l & 15;

    f32x4 acc0 = {0.f, 0.f, 0.f, 0.f};
    f32x4 acc1 = {0.f, 0.f, 0.f, 0.f};
    f32x4 acc2 = {0.f, 0.f, 0.f, 0.f};
    f32x4 acc3 = {0.f, 0.f, 0.f, 0.f};

    const __bf16* brow0 = &Bt[lr][quad * 8];
    const __bf16* brow1 = &Bt[16 + lr][quad * 8];
    const __bf16* brow2 = &Bt[32 + lr][quad * 8];
    const __bf16* brow3 = &Bt[48 + lr][quad * 8];

    #pragma unroll 3
    for (int ks = 0; ks < KSC; ++ks) {
        int ks_g = kh3 * KSC + ks;
        v8bf16 afrag = *(const v8bf16*)(wfrag + (((size_t)wv * KSTEPS + ks_g) * 64 + l) * 8);
        v8bf16 b0 = *(const v8bf16*)(brow0 + ks * 32);
        v8bf16 b1 = *(const v8bf16*)(brow1 + ks * 32);
        v8bf16 b2 = *(const v8bf16*)(brow2 + ks * 32);
        v8bf16 b3 = *(const v8bf16*)(brow3 + ks * 32);
        acc0 = __builtin_amdgcn_mfma_f32_16x16x32_bf16(afrag, b0, acc0, 0, 0, 0);
        acc1 = __builtin_amdgcn_mfma_f32_16x16x32_bf16(afrag, b1, acc1, 0, 0, 0);
        acc2 = __builtin_amdgcn_mfma_f32_16x16x32_bf16(afrag, b2, acc2, 0, 0, 0);
        acc3 = __builtin_amdgcn_mfma_f32_16x16x32_bf16(afrag, b3, acc3, 0, 0, 0);
    }

    // ---- epilogue: atomic accumulate into out ----
    int obase = wv * 16 + quad * 4;
    float* opb = out + (((size_t)(b * OC + obase)) << 12) + (i << 6) + lr;
    #pragma unroll
    for (int ph = 0; ph < 4; ++ph) {
        f32x4 a = (ph == 0) ? acc0 : (ph == 1) ? acc1 : (ph == 2) ? acc2 : acc3;
        float* op = opb + ph * 16;
        #pragma unroll
        for (int r = 0; r < 4; ++r)
            unsafeAtomicAdd(op + ((size_t)r << 12), a[r]);
    }
}

// ---------- round-5 fused fallback (verified) ----------
__global__ __launch_bounds__(512, 8) void deform_fused_kernel(
    const float* __restrict__ x, const float* __restrict__ off,
    const float* __restrict__ w, const __bf16* __restrict__ wfrag,
    const __bf16* __restrict__ xt, float* __restrict__ out, int mode)
{
    __shared__ __align__(16) __bf16 Bt[PX][LDBc];
    __shared__ __align__(8)  unsigned short sIdxP[NDESC][4];
    __shared__ __align__(8)  _Float16      sGP[NDESC][4];

    const int bidx = blockIdx.x;
    const int b   = bidx >> 8;
    const int i   = (bidx >> 2) & 63;
    const int j0  = ((bidx >> 1) & 1) * PX;
    const int oh  = bidx & 1;
    const int tid = threadIdx.x;

    if (tid < NDESC) {
        int k = tid >> 5, p = tid & 31;
        int j = j0 + p;
        float ox = off[(((b * 18) + 2 * k) * 64 + i) * 64 + j];
        float oy = off[(((b * 18) + 2 * k + 1) * 64 + i) * 64 + j];
        float px = (float)(i + k / 3) + ox;
        float py = (float)(j + k % 3) + oy;
        float fx = floorf(px), fy = floorf(py);
        int qltx = (int)fminf(fmaxf(fx, 0.f), 65.f);
        int qlty = (int)fminf(fmaxf(fy, 0.f), 65.f);
        int qrbx = (int)fminf(fmaxf(fx + 1.f, 0.f), 65.f);
        int qrby = (int)fminf(fmaxf(fy + 1.f, 0.f), 65.f);
        if (px < 1.f || px > 64.f) px = fx;
        if (py < 1.f || py > 64.f) py = fy;
        px = fminf(fmaxf(px, 0.f), 65.f);
        py = fminf(fmaxf(py, 0.f), 65.f);
        float wxl = 1.f + (float)qltx - px;
        float wxr = 1.f - ((float)qrbx - px);
        float wyl = 1.f + (float)qlty - py;
        float wyr = 1.f - ((float)qrby - py);
        float g[4] = { wxl * wyl, wxr * wyr, wxl * wyr, wxr * wyl };
        int qx[4] = { qltx, qrbx, qltx, qrbx };
        int qy[4] = { qlty, qrby, qrby, qlty };
        #pragma unroll
        for (int cr = 0; cr < 4; ++cr) {
            bool inb = (qx[cr] >= 1) && (qx[cr] <= 64) && (qy[cr] >= 1) && (qy[cr] <= 64);
            sIdxP[tid][cr] = inb ? (unsigned short)((qx[cr] - 1) * 64 + (qy[cr] - 1)) : 0;
            sGP[tid][cr]   = inb ? (_Float16)g[cr] : (_Float16)0.f;
        }
    }
    __syncthreads();

    const int l    = tid & 63;
    const int wv   = tid >> 6;
    const int ot   = oh * 4 + (wv & 3);
    const int ph   = wv >> 2;
    const int quad = l >> 4;
    const int lr   = l & 15;

    f32x4 acc = {0.f, 0.f, 0.f, 0.f};
    const __bf16* xtb = xt + ((size_t)b * 4096) * CIN;
    const float*  xb  = x + ((size_t)b * CIN << 12);
    const __bf16* brow = &Bt[ph * 16 + lr][quad * 8];

    for (int t = 0; t < 3; ++t) {
        if (mode == 2) {
            #pragma unroll 4
            for (int dd = 0; dd < KSC; ++dd) {
                int dl = wv * KSC + dd;
                int tap_l = dl >> 5, p = dl & 31;
                int d = t * 96 + dl;
                ushort4v id = *(const ushort4v*)&sIdxP[d][0];
                half4v   gh = *(const half4v*)&sGP[d][0];
                float s0 = 0.f, s1 = 0.f;
                #pragma unroll
                for (int cr = 0; cr < 4; ++cr) {
                    unsigned int v = *(const unsigned int*)(xtb + (size_t)id[cr] * CIN + 2 * l);
                    float c0v, c1v;
                    unsigned int lo = v << 16, hi = v & 0xffff0000u;
                    __builtin_memcpy(&c0v, &lo, 4);
                    __builtin_memcpy(&c1v, &hi, 4);
                    float gf = (float)gh[cr];
                    s0 += gf * c0v;
                    s1 += gf * c1v;
                }
                bf16x2 pr = { (__bf16)s0, (__bf16)s1 };
                *(bf16x2*)&Bt[p][tap_l * CIN + 2 * l] = pr;
            }
        } else {
            for (int dd = 0; dd < KSC; ++dd) {
                int dl = wv * KSC + dd;
                int tap_l = dl >> 5, p = dl & 31;
                int d = t * 96 + dl;
                ushort4v id = *(const ushort4v*)&sIdxP[d][0];
                half4v   gh = *(const half4v*)&sGP[d][0];
                float s0 = 0.f, s1 = 0.f;
                #pragma unroll
                for (int cr = 0; cr < 4; ++cr) {
                    float gf = (float)gh[cr];
                    s0 += gf * xb[((size_t)(2 * l) << 12) + id[cr]];
                    s1 += gf * xb[((size_t)(2 * l + 1) << 12) + id[cr]];
                }
                bf16x2 pr = { (__bf16)s0, (__bf16)s1 };
                *(bf16x2*)&Bt[p][tap_l * CIN + 2 * l] = pr;
            }
        }
        __syncthreads();

        #pragma unroll 4
        for (int ks = 0; ks < KSC; ++ks) {
            int ks_g = t * KSC + ks;
            v8bf16 bfrag = *(const v8bf16*)(brow + ks * 32);
            v8bf16 afrag;
            if (mode >= 1) {
                afrag = *(const v8bf16*)(wfrag + (((size_t)ot * KSTEPS + ks_g) * 64 + l) * 8);
            } else {
                int o = ot * 16 + lr;
                #pragma unroll
                for (int e = 0; e < 8; ++e) {
                    int k = ks_g * 32 + quad * 8 + e;
                    int tap = k >> 7, c = k & 127;
                    afrag[e] = (__bf16)w[(size_t)o * KTOT + c * NPT + tap];
                }
            }
            acc = __builtin_amdgcn_mfma_f32_16x16x32_bf16(afrag, bfrag, acc, 0, 0, 0);
        }
        if (t < 2) __syncthreads();
    }

    {
        int obase = ot * 16 + quad * 4;
        float* op = out + (((size_t)(b * OC + obase)) << 12) + (i << 6) + j0 + ph * 16 + lr;
        #pragma unroll
        for (int r = 0; r < 4; ++r)
            op[(size_t)r << 12] = acc[r];
    }
}

// standalone prep pieces for fallback modes
__global__ __launch_bounds__(256) void wfrag_kernel(const float* __restrict__ w,
                                                    __bf16* __restrict__ wfrag) {
    int t = blockIdx.x * 256 + threadIdx.x;
    if (t >= 8 * KSTEPS * 64) return;
    int lane = t & 63;
    int ks   = (t >> 6) % KSTEPS;
    int ot   = t / (KSTEPS * 64);
    int o    = ot * 16 + (lane & 15);
    v8bf16 frag;
    #pragma unroll
    for (int e = 0; e < 8; ++e) {
        int k   = ks * 32 + (lane >> 4) * 8 + e;
        int tap = k >> 7, c = k & 127;
        frag[e] = (__bf16)w[(size_t)o * KTOT + c * NPT + tap];
    }
    *(v8bf16*)(wfrag + (size_t)t * 8) = frag;
}

__global__ __launch_bounds__(256) void xpose_kernel(const float* __restrict__ x,
                                                    __bf16* __restrict__ xt) {
    __shared__ float tile[64][33];
    const int bidx = blockIdx.x;
    const int b   = bidx >> 8;
    const int hw0 = ((bidx >> 2) & 63) * 64;
    const int c0  = (bidx & 3) * 32;
    const int tid = threadIdx.x;
    #pragma unroll
    for (int r = 0; r < 8; ++r) {
        int c_l  = (tid >> 6) + r * 4;
        int hw_l = tid & 63;
        tile[hw_l][c_l] = x[((size_t)(b * CIN + c0 + c_l) << 12) + hw0 + hw_l];
    }
    __syncthreads();
    #pragma unroll
    for (int r = 0; r < 8; ++r) {
        int hw_l = (tid >> 5) + r * 8;
        int c_l  = tid & 31;
        xt[((size_t)(b * 4096 + hw0 + hw_l)) * CIN + c0 + c_l] = (__bf16)tile[hw_l][c_l];
    }
}

extern "C" void kernel_launch(void* const* d_in, const int* in_sizes, int n_in,
                              void* d_out, int out_size, void* d_ws, size_t ws_size,
                              hipStream_t stream) {
    const float* x   = (const float*)d_in[0];
    const float* off = (const float*)d_in[1];
    const float* w   = (const float*)d_in[2];
    float* out = (float*)d_out;

    const size_t wfrag_bytes = (size_t)OC * KTOT * sizeof(__bf16);        // 294912
    const size_t xt_bytes    = (size_t)4 * 4096 * CIN * sizeof(__bf16);   // 4 MB
    const size_t desc_bytes  = (size_t)DTOT * 16;                         // 2.36 MB

    int mode = 0;
    if (ws_size >= wfrag_bytes + xt_bytes + desc_bytes) mode = 3;
    else if (ws_size >= wfrag_bytes + xt_bytes) mode = 2;
    else if (ws_size >= wfrag_bytes) mode = 1;

    __bf16* wfrag = (__bf16*)d_ws;
    __bf16* xt    = (__bf16*)((char*)d_ws + wfrag_bytes);
    uint4*  desc  = (uint4*) ((char*)d_ws + wfrag_bytes + xt_bytes);

    if (mode == 3) {
        prep_kernel<<<PB_TOTAL, 256, 0, stream>>>(x, off, w, wfrag, xt, desc, out);
        splitk_kernel<<<4 * 64 * 3, 512, 0, stream>>>(desc, xt, wfrag, out);
    } else {
        if (mode >= 1)
            wfrag_kernel<<<(8 * KSTEPS * 64 + 255) / 256, 256, 0, stream>>>(w, wfrag);
        if (mode >= 2)
            xpose_kernel<<<4 * 64 * 4, 256, 0, stream>>>(x, xt);
        deform_fused_kernel<<<4 * 64 * 2 * 2, 512, 0, stream>>>(x, off, w, wfrag, xt, out, mode);
    }
}

// Round 10
// 95.548 us; speedup vs baseline: 1.0640x; 1.0640x over previous
//
#include <hip/hip_runtime.h>

// DeformConv2D b=4,c=128,H=W=64,outc=128,KS=3,PAD=1,N=9
// 2-launch pipeline (mode 3):
//   prep  : wfrag + xpose + desc + zero(out), fused, branch on blockIdx
//   splitk: grid 768, XCD-swizzled (b = (bidx&7)>>1), block = 64px x 128o,
//           taps 3kh..3kh+2. Staging: quarter-wave dwordx4 gathers (one VMEM
//           per corner per 4 descs), descs preloaded. Epilogue: atomicAdd.
// Fallback (mode<=2): round-5 fused kernel (verified).

typedef __bf16  v8bf16 __attribute__((ext_vector_type(8)));
typedef __bf16  bf16x2 __attribute__((ext_vector_type(2)));
typedef float   f32x4  __attribute__((ext_vector_type(4)));
typedef unsigned short ushort4v __attribute__((ext_vector_type(4)));
typedef _Float16 half4v __attribute__((ext_vector_type(4)));

#define CIN  128
#define NPT  9
#define KTOT 1152
#define OC   128
#define PX   32
#define NDESC (NPT * PX)
#define KSTEPS 36
#define KSC  12
#define LDBc 392
#define DTOT (9 * 4 * 64 * 64)   // 147456
#define PXR  64                  // full row
#define LDR  392                 // 3*128+8

// prep grid layout
#define PB_WFRAG 72
#define PB_XPOSE 1024
#define PB_DESC  576
#define PB_ZERO  2048
#define PB_TOTAL (PB_WFRAG + PB_XPOSE + PB_DESC + PB_ZERO)

__device__ __forceinline__ void desc_compute(const float* __restrict__ off, int t,
                                             uint4* __restrict__ desc) {
    int j   = t & 63;
    int i   = (t >> 6) & 63;
    int b   = (t >> 12) & 3;
    int tap = t >> 14;

    float ox = off[(((b * 18) + 2 * tap) << 12) + (i << 6) + j];
    float oy = off[(((b * 18) + 2 * tap + 1) << 12) + (i << 6) + j];
    float px = (float)(i + tap / 3) + ox;
    float py = (float)(j + tap % 3) + oy;
    float fx = floorf(px), fy = floorf(py);
    int qltx = (int)fminf(fmaxf(fx, 0.f), 65.f);
    int qlty = (int)fminf(fmaxf(fy, 0.f), 65.f);
    int qrbx = (int)fminf(fmaxf(fx + 1.f, 0.f), 65.f);
    int qrby = (int)fminf(fmaxf(fy + 1.f, 0.f), 65.f);
    if (px < 1.f || px > 64.f) px = fx;
    if (py < 1.f || py > 64.f) py = fy;
    px = fminf(fmaxf(px, 0.f), 65.f);
    py = fminf(fmaxf(py, 0.f), 65.f);
    float wxl = 1.f + (float)qltx - px;
    float wxr = 1.f - ((float)qrbx - px);
    float wyl = 1.f + (float)qlty - py;
    float wyr = 1.f - ((float)qrby - py);
    float g[4] = { wxl * wyl, wxr * wyr, wxl * wyr, wxr * wyl };
    int qx[4] = { qltx, qrbx, qltx, qrbx };
    int qy[4] = { qlty, qrby, qrby, qlty };
    unsigned short idx[4];
    half4v gh;
    #pragma unroll
    for (int cr = 0; cr < 4; ++cr) {
        bool inb = (qx[cr] >= 1) && (qx[cr] <= 64) && (qy[cr] >= 1) && (qy[cr] <= 64);
        idx[cr] = inb ? (unsigned short)((qx[cr] - 1) * 64 + (qy[cr] - 1)) : 0;
        gh[cr]  = inb ? (_Float16)g[cr] : (_Float16)0.f;
    }
    uint4 rec;
    rec.x = (unsigned)idx[0] | ((unsigned)idx[1] << 16);
    rec.y = (unsigned)idx[2] | ((unsigned)idx[3] << 16);
    __builtin_memcpy(&rec.z, &gh, 8);
    int d = (((b << 6) + i) * 64 + j) * 9 + tap;
    desc[d] = rec;
}

// ---------- fused prep: wfrag | xpose | desc | zero(out) ----------
__global__ __launch_bounds__(256) void prep_kernel(
    const float* __restrict__ x, const float* __restrict__ off,
    const float* __restrict__ w, __bf16* __restrict__ wfrag,
    __bf16* __restrict__ xt, uint4* __restrict__ desc,
    float* __restrict__ out)
{
    __shared__ float tile[64][33];
    const int bid = blockIdx.x;
    const int tid = threadIdx.x;

    if (bid < PB_WFRAG) {
        int t = bid * 256 + tid;
        if (t < 8 * KSTEPS * 64) {
            int lane = t & 63;
            int ks   = (t >> 6) % KSTEPS;
            int ot   = t / (KSTEPS * 64);
            int o    = ot * 16 + (lane & 15);
            v8bf16 frag;
            #pragma unroll
            for (int e = 0; e < 8; ++e) {
                int k   = ks * 32 + (lane >> 4) * 8 + e;
                int tap = k >> 7, c = k & 127;
                frag[e] = (__bf16)w[(size_t)o * KTOT + c * NPT + tap];
            }
            *(v8bf16*)(wfrag + (size_t)t * 8) = frag;
        }
    } else if (bid < PB_WFRAG + PB_XPOSE) {
        const int bidx = bid - PB_WFRAG;
        const int b   = bidx >> 8;
        const int hw0 = ((bidx >> 2) & 63) * 64;
        const int c0  = (bidx & 3) * 32;
        #pragma unroll
        for (int r = 0; r < 8; ++r) {
            int c_l  = (tid >> 6) + r * 4;
            int hw_l = tid & 63;
            tile[hw_l][c_l] = x[((size_t)(b * CIN + c0 + c_l) << 12) + hw0 + hw_l];
        }
        __syncthreads();
        #pragma unroll
        for (int r = 0; r < 8; ++r) {
            int hw_l = (tid >> 5) + r * 8;
            int c_l  = tid & 31;
            xt[((size_t)(b * 4096 + hw0 + hw_l)) * CIN + c0 + c_l] = (__bf16)tile[hw_l][c_l];
        }
    } else if (bid < PB_WFRAG + PB_XPOSE + PB_DESC) {
        int t = (bid - PB_WFRAG - PB_XPOSE) * 256 + tid;
        if (t < DTOT) desc_compute(off, t, desc);
    } else {
        int t = (bid - PB_WFRAG - PB_XPOSE - PB_DESC) * 256 + tid;
        f32x4 z = {0.f, 0.f, 0.f, 0.f};
        *(f32x4*)(out + (size_t)t * 4) = z;
    }
}

// ---------- split-K=3 full-row kernel, quarter-wave gathers, atomic epilogue ----------
__global__ __launch_bounds__(512, 6) void splitk_kernel(
    const uint4* __restrict__ desc, const __bf16* __restrict__ xt,
    const __bf16* __restrict__ wfrag, float* __restrict__ out)
{
    __shared__ __align__(16) __bf16 Bt[PXR][LDR];   // 50176 B

    // XCD-aware swizzle: b = XCD pair; 96 blocks/XCD cover (i, kh) for that b
    const int bidx = blockIdx.x;     // 768
    const int b    = (bidx & 7) >> 1;
    const int sub  = ((bidx >> 3) << 1) | (bidx & 1);   // [0,192)
    const int kh3  = sub % 3;
    const int i    = sub / 3;        // [0,64)
    const int tid  = threadIdx.x;

    const int tap0 = kh3 * 3;

    const int l  = tid & 63;
    const int wv = tid >> 6;            // 0..7

    const __bf16* xtb = xt + (((size_t)b << 12) * CIN);
    const int pix_base = ((b << 6) + i) * 64;

    // ---- stage: 192 descs (3 taps x 64 px), 24 per wave ----
    // quarter-wave: q = l>>4 picks desc, ll = l&15 covers 8 channels x 16 lanes
    {
        const int q  = l >> 4;
        const int ll = l & 15;

        uint4 qd[6];
        int   pp[6], tt[6];
        #pragma unroll
        for (int m = 0; m < 6; ++m) {
            int dl = wv * 24 + m * 4 + q;    // [0,192)
            tt[m] = dl >> 6;
            pp[m] = dl & 63;
            int d = (pix_base + pp[m]) * 9 + tap0 + tt[m];
            qd[m] = desc[d];
        }

        #pragma unroll
        for (int m = 0; m < 6; ++m) {
            unsigned short idx[4] = {
                (unsigned short)(qd[m].x & 0xffff), (unsigned short)(qd[m].x >> 16),
                (unsigned short)(qd[m].y & 0xffff), (unsigned short)(qd[m].y >> 16) };
            half4v gh;
            unsigned int zz[2] = { qd[m].z, qd[m].w };
            __builtin_memcpy(&gh, &zz, 8);

            float s[8] = {0.f,0.f,0.f,0.f,0.f,0.f,0.f,0.f};
            #pragma unroll
            for (int cr = 0; cr < 4; ++cr) {
                uint4 v = *(const uint4*)(xtb + (size_t)idx[cr] * CIN + 8 * ll);
                float gf = (float)gh[cr];
                unsigned int dw[4] = { v.x, v.y, v.z, v.w };
                #pragma unroll
                for (int e = 0; e < 4; ++e) {
                    float clo, chi;
                    unsigned int lo = dw[e] << 16, hi = dw[e] & 0xffff0000u;
                    __builtin_memcpy(&clo, &lo, 4);
                    __builtin_memcpy(&chi, &hi, 4);
                    s[2 * e]     += gf * clo;
                    s[2 * e + 1] += gf * chi;
                }
            }
            v8bf16 pr;
            #pragma unroll
            for (int e = 0; e < 8; ++e) pr[e] = (__bf16)s[e];
            *(v8bf16*)&Bt[pp[m]][tt[m] * CIN + 8 * ll] = pr;
        }
    }
    __syncthreads();

    // ---- MFMA: wave = ot (wv), 4 px-quarters share each afrag ----
    const int quad = l >> 4;
    const int lr   = l & 15;

    f32x4 acc0 = {0.f, 0.f, 0.f, 0.f};
    f32x4 acc1 = {0.f, 0.f, 0.f, 0.f};
    f32x4 acc2 = {0.f, 0.f, 0.f, 0.f};
    f32x4 acc3 = {0.f, 0.f, 0.f, 0.f};

    const __bf16* brow0 = &Bt[lr][quad * 8];
    const __bf16* brow1 = &Bt[16 + lr][quad * 8];
    const __bf16* brow2 = &Bt[32 + lr][quad * 8];
    const __bf16* brow3 = &Bt[48 + lr][quad * 8];

    #pragma unroll 3
    for (int ks = 0; ks < KSC; ++ks) {
        int ks_g = kh3 * KSC + ks;
        v8bf16 afrag = *(const v8bf16*)(wfrag + (((size_t)wv * KSTEPS + ks_g) * 64 + l) * 8);
        v8bf16 b0 = *(const v8bf16*)(brow0 + ks * 32);
        v8bf16 b1 = *(const v8bf16*)(brow1 + ks * 32);
        v8bf16 b2 = *(const v8bf16*)(brow2 + ks * 32);
        v8bf16 b3 = *(const v8bf16*)(brow3 + ks * 32);
        acc0 = __builtin_amdgcn_mfma_f32_16x16x32_bf16(afrag, b0, acc0, 0, 0, 0);
        acc1 = __builtin_amdgcn_mfma_f32_16x16x32_bf16(afrag, b1, acc1, 0, 0, 0);
        acc2 = __builtin_amdgcn_mfma_f32_16x16x32_bf16(afrag, b2, acc2, 0, 0, 0);
        acc3 = __builtin_amdgcn_mfma_f32_16x16x32_bf16(afrag, b3, acc3, 0, 0, 0);
    }

    // ---- epilogue: atomic accumulate into out ----
    int obase = wv * 16 + quad * 4;
    float* opb = out + (((size_t)(b * OC + obase)) << 12) + (i << 6) + lr;
    #pragma unroll
    for (int ph = 0; ph < 4; ++ph) {
        f32x4 a = (ph == 0) ? acc0 : (ph == 1) ? acc1 : (ph == 2) ? acc2 : acc3;
        float* op = opb + ph * 16;
        #pragma unroll
        for (int r = 0; r < 4; ++r)
            unsafeAtomicAdd(op + ((size_t)r << 12), a[r]);
    }
}

// ---------- round-5 fused fallback (verified) ----------
__global__ __launch_bounds__(512, 8) void deform_fused_kernel(
    const float* __restrict__ x, const float* __restrict__ off,
    const float* __restrict__ w, const __bf16* __restrict__ wfrag,
    const __bf16* __restrict__ xt, float* __restrict__ out, int mode)
{
    __shared__ __align__(16) __bf16 Bt[PX][LDBc];
    __shared__ __align__(8)  unsigned short sIdxP[NDESC][4];
    __shared__ __align__(8)  _Float16      sGP[NDESC][4];

    const int bidx = blockIdx.x;
    const int b   = bidx >> 8;
    const int i   = (bidx >> 2) & 63;
    const int j0  = ((bidx >> 1) & 1) * PX;
    const int oh  = bidx & 1;
    const int tid = threadIdx.x;

    if (tid < NDESC) {
        int k = tid >> 5, p = tid & 31;
        int j = j0 + p;
        float ox = off[(((b * 18) + 2 * k) * 64 + i) * 64 + j];
        float oy = off[(((b * 18) + 2 * k + 1) * 64 + i) * 64 + j];
        float px = (float)(i + k / 3) + ox;
        float py = (float)(j + k % 3) + oy;
        float fx = floorf(px), fy = floorf(py);
        int qltx = (int)fminf(fmaxf(fx, 0.f), 65.f);
        int qlty = (int)fminf(fmaxf(fy, 0.f), 65.f);
        int qrbx = (int)fminf(fmaxf(fx + 1.f, 0.f), 65.f);
        int qrby = (int)fminf(fmaxf(fy + 1.f, 0.f), 65.f);
        if (px < 1.f || px > 64.f) px = fx;
        if (py < 1.f || py > 64.f) py = fy;
        px = fminf(fmaxf(px, 0.f), 65.f);
        py = fminf(fmaxf(py, 0.f), 65.f);
        float wxl = 1.f + (float)qltx - px;
        float wxr = 1.f - ((float)qrbx - px);
        float wyl = 1.f + (float)qlty - py;
        float wyr = 1.f - ((float)qrby - py);
        float g[4] = { wxl * wyl, wxr * wyr, wxl * wyr, wxr * wyl };
        int qx[4] = { qltx, qrbx, qltx, qrbx };
        int qy[4] = { qlty, qrby, qrby, qlty };
        #pragma unroll
        for (int cr = 0; cr < 4; ++cr) {
            bool inb = (qx[cr] >= 1) && (qx[cr] <= 64) && (qy[cr] >= 1) && (qy[cr] <= 64);
            sIdxP[tid][cr] = inb ? (unsigned short)((qx[cr] - 1) * 64 + (qy[cr] - 1)) : 0;
            sGP[tid][cr]   = inb ? (_Float16)g[cr] : (_Float16)0.f;
        }
    }
    __syncthreads();

    const int l    = tid & 63;
    const int wv   = tid >> 6;
    const int ot   = oh * 4 + (wv & 3);
    const int ph   = wv >> 2;
    const int quad = l >> 4;
    const int lr   = l & 15;

    f32x4 acc = {0.f, 0.f, 0.f, 0.f};
    const __bf16* xtb = xt + ((size_t)b * 4096) * CIN;
    const float*  xb  = x + ((size_t)b * CIN << 12);
    const __bf16* brow = &Bt[ph * 16 + lr][quad * 8];

    for (int t = 0; t < 3; ++t) {
        if (mode == 2) {
            #pragma unroll 4
            for (int dd = 0; dd < KSC; ++dd) {
                int dl = wv * KSC + dd;
                int tap_l = dl >> 5, p = dl & 31;
                int d = t * 96 + dl;
                ushort4v id = *(const ushort4v*)&sIdxP[d][0];
                half4v   gh = *(const half4v*)&sGP[d][0];
                float s0 = 0.f, s1 = 0.f;
                #pragma unroll
                for (int cr = 0; cr < 4; ++cr) {
                    unsigned int v = *(const unsigned int*)(xtb + (size_t)id[cr] * CIN + 2 * l);
                    float c0v, c1v;
                    unsigned int lo = v << 16, hi = v & 0xffff0000u;
                    __builtin_memcpy(&c0v, &lo, 4);
                    __builtin_memcpy(&c1v, &hi, 4);
                    float gf = (float)gh[cr];
                    s0 += gf * c0v;
                    s1 += gf * c1v;
                }
                bf16x2 pr = { (__bf16)s0, (__bf16)s1 };
                *(bf16x2*)&Bt[p][tap_l * CIN + 2 * l] = pr;
            }
        } else {
            for (int dd = 0; dd < KSC; ++dd) {
                int dl = wv * KSC + dd;
                int tap_l = dl >> 5, p = dl & 31;
                int d = t * 96 + dl;
                ushort4v id = *(const ushort4v*)&sIdxP[d][0];
                half4v   gh = *(const half4v*)&sGP[d][0];
                float s0 = 0.f, s1 = 0.f;
                #pragma unroll
                for (int cr = 0; cr < 4; ++cr) {
                    float gf = (float)gh[cr];
                    s0 += gf * xb[((size_t)(2 * l) << 12) + id[cr]];
                    s1 += gf * xb[((size_t)(2 * l + 1) << 12) + id[cr]];
                }
                bf16x2 pr = { (__bf16)s0, (__bf16)s1 };
                *(bf16x2*)&Bt[p][tap_l * CIN + 2 * l] = pr;
            }
        }
        __syncthreads();

        #pragma unroll 4
        for (int ks = 0; ks < KSC; ++ks) {
            int ks_g = t * KSC + ks;
            v8bf16 bfrag = *(const v8bf16*)(brow + ks * 32);
            v8bf16 afrag;
            if (mode >= 1) {
                afrag = *(const v8bf16*)(wfrag + (((size_t)ot * KSTEPS + ks_g) * 64 + l) * 8);
            } else {
                int o = ot * 16 + lr;
                #pragma unroll
                for (int e = 0; e < 8; ++e) {
                    int k = ks_g * 32 + quad * 8 + e;
                    int tap = k >> 7, c = k & 127;
                    afrag[e] = (__bf16)w[(size_t)o * KTOT + c * NPT + tap];
                }
            }
            acc = __builtin_amdgcn_mfma_f32_16x16x32_bf16(afrag, bfrag, acc, 0, 0, 0);
        }
        if (t < 2) __syncthreads();
    }

    {
        int obase = ot * 16 + quad * 4;
        float* op = out + (((size_t)(b * OC + obase)) << 12) + (i << 6) + j0 + ph * 16 + lr;
        #pragma unroll
        for (int r = 0; r < 4; ++r)
            op[(size_t)r << 12] = acc[r];
    }
}

// standalone prep pieces for fallback modes
__global__ __launch_bounds__(256) void wfrag_kernel(const float* __restrict__ w,
                                                    __bf16* __restrict__ wfrag) {
    int t = blockIdx.x * 256 + threadIdx.x;
    if (t >= 8 * KSTEPS * 64) return;
    int lane = t & 63;
    int ks   = (t >> 6) % KSTEPS;
    int ot   = t / (KSTEPS * 64);
    int o    = ot * 16 + (lane & 15);
    v8bf16 frag;
    #pragma unroll
    for (int e = 0; e < 8; ++e) {
        int k   = ks * 32 + (lane >> 4) * 8 + e;
        int tap = k >> 7, c = k & 127;
        frag[e] = (__bf16)w[(size_t)o * KTOT + c * NPT + tap];
    }
    *(v8bf16*)(wfrag + (size_t)t * 8) = frag;
}

__global__ __launch_bounds__(256) void xpose_kernel(const float* __restrict__ x,
                                                    __bf16* __restrict__ xt) {
    __shared__ float tile[64][33];
    const int bidx = blockIdx.x;
    const int b   = bidx >> 8;
    const int hw0 = ((bidx >> 2) & 63) * 64;
    const int c0  = (bidx & 3) * 32;
    const int tid = threadIdx.x;
    #pragma unroll
    for (int r = 0; r < 8; ++r) {
        int c_l  = (tid >> 6) + r * 4;
        int hw_l = tid & 63;
        tile[hw_l][c_l] = x[((size_t)(b * CIN + c0 + c_l) << 12) + hw0 + hw_l];
    }
    __syncthreads();
    #pragma unroll
    for (int r = 0; r < 8; ++r) {
        int hw_l = (tid >> 5) + r * 8;
        int c_l  = tid & 31;
        xt[((size_t)(b * 4096 + hw0 + hw_l)) * CIN + c0 + c_l] = (__bf16)tile[hw_l][c_l];
    }
}

extern "C" void kernel_launch(void* const* d_in, const int* in_sizes, int n_in,
                              void* d_out, int out_size, void* d_ws, size_t ws_size,
                              hipStream_t stream) {
    const float* x   = (const float*)d_in[0];
    const float* off = (const float*)d_in[1];
    const float* w   = (const float*)d_in[2];
    float* out = (float*)d_out;

    const size_t wfrag_bytes = (size_t)OC * KTOT * sizeof(__bf16);        // 294912
    const size_t xt_bytes    = (size_t)4 * 4096 * CIN * sizeof(__bf16);   // 4 MB
    const size_t desc_bytes  = (size_t)DTOT * 16;                         // 2.36 MB

    int mode = 0;
    if (ws_size >= wfrag_bytes + xt_bytes + desc_bytes) mode = 3;
    else if (ws_size >= wfrag_bytes + xt_bytes) mode = 2;
    else if (ws_size >= wfrag_bytes) mode = 1;

    __bf16* wfrag = (__bf16*)d_ws;
    __bf16* xt    = (__bf16*)((char*)d_ws + wfrag_bytes);
    uint4*  desc  = (uint4*) ((char*)d_ws + wfrag_bytes + xt_bytes);

    if (mode == 3) {
        prep_kernel<<<PB_TOTAL, 256, 0, stream>>>(x, off, w, wfrag, xt, desc, out);
        splitk_kernel<<<4 * 64 * 3, 512, 0, stream>>>(desc, xt, wfrag, out);
    } else {
        if (mode >= 1)
            wfrag_kernel<<<(8 * KSTEPS * 64 + 255) / 256, 256, 0, stream>>>(w, wfrag);
        if (mode >= 2)
            xpose_kernel<<<4 * 64 * 4, 256, 0, stream>>>(x, xt);
        deform_fused_kernel<<<4 * 64 * 2 * 2, 512, 0, stream>>>(x, off, w, wfrag, xt, out, mode);
    }
}